// Round 1
// baseline (343.202 us; speedup 1.0000x reference)
//
#include <hip/hip_runtime.h>

#define THRESH 1.0f

// ---------------------------------------------------------------------------
// Kernel 1: per-edge "any batch exceeds threshold" flags.
// Edge e in [0,1984):
//   e <  992 : h-edge, i=e/31, j=e%31, between cells (i,j) and (i,j+1)
//   e >= 992 : v-edge, e2=e-992, i=e2>>5, j=e2&31, between (i,j) and (i+1,j)
// One block per edge; loops over batches with early exit once exceeded
// (sum-of-squares is monotone in terms, and sqrt(s)>1 <=> s>1).
// Single writer per flag -> no zero-init of workspace needed, no atomics.
// ---------------------------------------------------------------------------
__global__ __launch_bounds__(256) void edge_flags_kernel(
    const float* __restrict__ x, int* __restrict__ flags) {
  __shared__ float red[4];
  __shared__ int sdone;
  const int e = blockIdx.x;
  const int t = threadIdx.x;
  if (t == 0) sdone = 0;
  __syncthreads();

  int p0, p1;
  if (e < 992) {
    int i = e / 31; int j = e - i * 31;
    p0 = i * 32 + j; p1 = p0 + 1;
  } else {
    int e2 = e - 992; int i = e2 >> 5; int j = e2 & 31;
    p0 = i * 32 + j; p1 = p0 + 32;
  }

  const int lane = t & 63;
  const int wid  = t >> 6;

  for (int b = 0; b < 64; ++b) {
    float s = 0.0f;
    if (t < 192) {  // 192 float4 = 768 floats per row
      const float4* A = (const float4*)(x + ((size_t)b * 1024 + p0) * 768);
      const float4* B = (const float4*)(x + ((size_t)b * 1024 + p1) * 768);
      float4 va = A[t];
      float4 vb = B[t];
      float dx = va.x - vb.x, dy = va.y - vb.y;
      float dz = va.z - vb.z, dw = va.w - vb.w;
      s = dx * dx + dy * dy + dz * dz + dw * dw;
    }
#pragma unroll
    for (int off = 32; off > 0; off >>= 1) s += __shfl_down(s, off, 64);
    if (lane == 0) red[wid] = s;
    __syncthreads();
    if (t == 0) {
      float tot = (red[0] + red[1]) + (red[2] + red[3]);
      if (tot > THRESH) sdone = 1;
    }
    __syncthreads();
    if (sdone) break;  // uniform across block (shared var)
  }
  if (t == 0) flags[e] = sdone;
}

// ---------------------------------------------------------------------------
// Kernel 2: combine edge flags into a per-cell mask over n = i*32+j.
// mask[n] = 1 iff cell is interior AND any of its 4 edges exceeded.
// ---------------------------------------------------------------------------
__global__ void mask_kernel(const int* __restrict__ flags,
                            int* __restrict__ mask) {
  const int n = threadIdx.x;  // 1024 threads, 1 block
  const int i = n >> 5, j = n & 31;
  int m = 0;
  if (i >= 1 && i <= 30 && j >= 1 && j <= 30) {
    const int* fh = flags;        // [32][31]
    const int* fv = flags + 992;  // [31][32]
    m = fh[i * 31 + (j - 1)] | fh[i * 31 + j] |
        fv[(i - 1) * 32 + j] | fv[i * 32 + j];
  }
  mask[n] = m;
}

// ---------------------------------------------------------------------------
// Kernel 3: apply. One block per (b, n); 192 lanes = 192 float4 = 768 floats.
// mask[n] is a block-uniform scalar load -> no intra-block divergence.
// Neighbor offsets in float4 units: +-192 (left/right), +-32*192 (up/down).
// ---------------------------------------------------------------------------
__global__ __launch_bounds__(192) void apply_kernel(
    const float* __restrict__ x, const int* __restrict__ mask,
    float* __restrict__ out) {
  const int bn = blockIdx.x;        // b*1024 + n
  const int n  = bn & 1023;
  const int t  = threadIdx.x;
  const size_t base = (size_t)bn * 192 + t;
  const float4* xv = (const float4*)x;
  float4* ov = (float4*)out;

  float4 c = xv[base];
  if (mask[n]) {
    float4 l = xv[base - 192];
    float4 r = xv[base + 192];
    float4 u = xv[base - 32 * 192];
    float4 d = xv[base + 32 * 192];
    float4 res;
    res.x = 0.5f * c.x + 0.125f * ((l.x + r.x) + (u.x + d.x));
    res.y = 0.5f * c.y + 0.125f * ((l.y + r.y) + (u.y + d.y));
    res.z = 0.5f * c.z + 0.125f * ((l.z + r.z) + (u.z + d.z));
    res.w = 0.5f * c.w + 0.125f * ((l.w + r.w) + (u.w + d.w));
    ov[base] = res;
  } else {
    ov[base] = c;
  }
}

extern "C" void kernel_launch(void* const* d_in, const int* in_sizes, int n_in,
                              void* d_out, int out_size, void* d_ws,
                              size_t ws_size, hipStream_t stream) {
  const float* x = (const float*)d_in[0];
  float* out = (float*)d_out;
  int* flags = (int*)d_ws;     // 1984 ints
  int* mask  = flags + 1984;   // 1024 ints  (total 12 KiB of ws)

  edge_flags_kernel<<<1984, 256, 0, stream>>>(x, flags);
  mask_kernel<<<1, 1024, 0, stream>>>(flags, mask);
  apply_kernel<<<64 * 1024, 192, 0, stream>>>(x, mask, out);
}